// Round 8
// baseline (51.377 us; speedup 1.0000x reference)
//
#include <hip/hip_runtime.h>

#define RPW  16      // rows per wave; block = 1 wave = 64 lanes
#define TPB  64
#define XDIM 99
#define NJ   26
#define OUTW 78

__device__ __forceinline__ void rodrigues(float ax, float ay, float az, float* R) {
    const float EPS = 1.1920928955078125e-07f;   // np.finfo(np.float32).eps
    float t = sqrtf(ax*ax + ay*ay + az*az);
    float inv = 1.0f / (t + EPS);
    float r0 = ax*inv, r1 = ay*inv, r2 = az*inv;
    float s = __sinf(t);
    float c = __cosf(t);
    float omc = 1.0f - c;
    float r00 = r0*r0, r11 = r1*r1, r22 = r2*r2;
    float r01 = r0*r1, r02 = r0*r2, r12 = r1*r2;
    R[0] = 1.0f - omc*(r11 + r22);
    R[1] = -s*r2 + omc*r01;
    R[2] =  s*r1 + omc*r02;
    R[3] =  s*r2 + omc*r01;
    R[4] = 1.0f - omc*(r00 + r22);
    R[5] = -s*r0 + omc*r12;
    R[6] = -s*r1 + omc*r02;
    R[7] =  s*r0 + omc*r12;
    R[8] = 1.0f - omc*(r00 + r11);
}

__global__ __launch_bounds__(TPB, 6) void skel_fk(const float* __restrict__ x,
                                                  const float* __restrict__ off,
                                                  float* __restrict__ out) {
    __shared__ float buf[RPW * XDIM];            // 6336 B, wave-private
    const int t = threadIdx.x;
    const long long row0 = (long long)blockIdx.x * RPW;

    // ---- stage 16 rows: one contiguous 6336 B slab, float4-coalesced ----
    {
        const float4* src4 = reinterpret_cast<const float4*>(x + row0 * XDIM);
        float4* dst4 = reinterpret_cast<float4*>(buf);
        #pragma unroll
        for (int j = 0; j < 7; ++j) {            // 396 float4 total
            int m = t + j * TPB;
            if (m < RPW * XDIM / 4) dst4[m] = src4[m];
        }
    }
    __syncthreads();                             // 1-wave block: no cross-wave wait

    const int r  = t >> 2;                       // row 0..15
    const int k3 = t & 3;                        // lane-within-row
    const int k  = (k3 < 3) ? k3 : 2;            // lane 3 duplicates column 2
    const float* row = &buf[r * XDIM];

    // slot tables (slot 0 = hip, slots 1..25 follow ORDER)
    constexpr int OFF_IDX[NJ] = {0,1,2,3,4,6,7,8,9,11,12,13,14,15,16,17,18,19,20,22,24,25,26,27,28,30};
    constexpr int PAR[NJ]     = {-1,0,1,2,3,0,5,6,7,0,9,10,11,12,10,14,15,16,17,17,10,20,21,22,23,23};

    float ac[NJ][3];   // column k of ang[slot]; compile-time indices -> registers
    float pp[NJ];      // component k of pos[slot]

    {
        float R[9];
        rodrigues(row[3], row[4], row[5], R);
        ac[0][0] = (k == 0) ? R[0] : ((k == 1) ? R[1] : R[2]);
        ac[0][1] = (k == 0) ? R[3] : ((k == 1) ? R[4] : R[5]);
        ac[0][2] = (k == 0) ? R[6] : ((k == 1) ? R[7] : R[8]);
        pp[0] = off[k] + row[k];
    }

    #pragma unroll
    for (int s = 1; s < NJ; ++s) {
        const int i  = OFF_IDX[s];
        const int pa = PAR[s];
        float L[9];
        rodrigues(row[3*i+3], row[3*i+4], row[3*i+5], L);
        const float o0 = off[3*i], o1 = off[3*i+1], o2 = off[3*i+2];  // uniform
        pp[s] = o0*ac[pa][0] + o1*ac[pa][1] + o2*ac[pa][2] + pp[pa];
        ac[s][0] = L[0]*ac[pa][0] + L[1]*ac[pa][1] + L[2]*ac[pa][2];
        ac[s][1] = L[3]*ac[pa][0] + L[4]*ac[pa][1] + L[5]*ac[pa][2];
        ac[s][2] = L[6]*ac[pa][0] + L[7]*ac[pa][1] + L[8]*ac[pa][2];
    }
    __syncthreads();                             // all buf reads complete (wave-local)

    // ---- pos transpose into (dead) input region: banks (3r+3s+k)%32, <=2-way ----
    if (k3 < 3) {
        #pragma unroll
        for (int s = 0; s < NJ; ++s)
            buf[r * XDIM + 3*s + k] = pp[s];
    }
    __syncthreads();

    // ---- flush: contiguous 4992 B out slab, full 64B lines, single touch ----
    {
        float* ob = out + row0 * OUTW;
        #pragma unroll
        for (int j = 0; j < 20; ++j) {           // 1248 dwords total
            int m = t + j * TPB;
            if (m < RPW * OUTW) {
                int rr = m / OUTW;               // const divisor -> magic mul
                int cc = m - rr * OUTW;
                ob[m] = buf[rr * XDIM + cc];
            }
        }
    }
}

extern "C" void kernel_launch(void* const* d_in, const int* in_sizes, int n_in,
                              void* d_out, int out_size, void* d_ws, size_t ws_size,
                              hipStream_t stream) {
    const float* x   = (const float*)d_in[0];
    const float* off = (const float*)d_in[1];
    float* out = (float*)d_out;
    const int B = in_sizes[0] / XDIM;      // 262144
    const int grid = B / RPW;              // 16384
    skel_fk<<<grid, TPB, 0, stream>>>(x, off, out);
}

// Round 10
// 40.111 us; speedup vs baseline: 1.2809x; 1.2809x over previous
//
#include <hip/hip_runtime.h>

#define ROWS 64      // rows per block
#define TPB  192     // 3 waves: wave k owns matrix column k for all 64 rows
#define XDIM 99
#define NJ   26
#define OUTW 78      // output floats per row

// ~1-2 ULP primitives; output threshold is 0.309 ABSOLUTE (measured slack 5x) -> safe
__device__ __forceinline__ float fast_rcp(float a)  { return __builtin_amdgcn_rcpf(a); }
__device__ __forceinline__ float fast_sqrt(float a) { return __builtin_amdgcn_sqrtf(a); }

__device__ __forceinline__ void rodrigues(float ax, float ay, float az, float* R) {
    const float EPS = 1.1920928955078125e-07f;   // np.finfo(np.float32).eps
    float t = fast_sqrt(ax*ax + ay*ay + az*az);
    float inv = fast_rcp(t + EPS);
    float r0 = ax*inv, r1 = ay*inv, r2 = az*inv;
    float s = __sinf(t);
    float c = __cosf(t);
    float omc = 1.0f - c;
    float r00 = r0*r0, r11 = r1*r1, r22 = r2*r2;
    float r01 = r0*r1, r02 = r0*r2, r12 = r1*r2;
    R[0] = 1.0f - omc*(r11 + r22);
    R[1] = -s*r2 + omc*r01;
    R[2] =  s*r1 + omc*r02;
    R[3] =  s*r2 + omc*r01;
    R[4] = 1.0f - omc*(r00 + r22);
    R[5] = -s*r0 + omc*r12;
    R[6] = -s*r1 + omc*r02;
    R[7] =  s*r0 + omc*r12;
    R[8] = 1.0f - omc*(r00 + r11);
}

__global__ __launch_bounds__(TPB, 8) void skel_fk(const float* __restrict__ x,
                                                  const float* __restrict__ off,
                                                  float* __restrict__ out) {
    __shared__ float buf[ROWS * XDIM];           // 25344 B = 3 waves x 8448 B slabs
    const int t = threadIdx.x;
    const int w = t >> 6;                        // wave id 0..2 (uniform per wave)
    const int l = t & 63;                        // lane
    const int row0 = blockIdx.x * ROWS;

    // ---- stage via global_load_lds: wave w DMAs bytes [w*8448, w*8448+8448)
    //      of the block slab. 8 x 16B-wide (1024B/instr) + 1 x 4B tail (256B).
    //      LDS dest = wave-uniform base + lane*size (linear slab -> exact fit). ----
    {
        const float* gsrc = x + (long long)row0 * XDIM;  // block slab base
        const float* gw = gsrc + w * 2112 + l * 4;       // lane's 16B within wave slab
        float* lw = buf + w * 2112;                      // wave-uniform LDS base
        #pragma unroll
        for (int j = 0; j < 8; ++j) {
            __builtin_amdgcn_global_load_lds(
                (const __attribute__((address_space(1))) unsigned int*)(gw + j * 256),
                (__attribute__((address_space(3))) unsigned int*)(lw + j * 256),
                16, 0, 0);
        }
        __builtin_amdgcn_global_load_lds(
            (const __attribute__((address_space(1))) unsigned int*)(gsrc + w * 2112 + 2048 + l),
            (__attribute__((address_space(3))) unsigned int*)(buf + w * 2112 + 2048),
            4, 0, 0);
    }
    __syncthreads();                             // implies vmcnt(0) drain

    const int r = l;                             // compute phase: lane = row, wave = column
    const int k = w;
    float* wrow = &buf[r * XDIM];                // non-const: pos transpose writes here
    const float* row = wrow;

    // slot tables (slot 0 = hip, slots 1..25 follow ORDER)
    constexpr int OFF_IDX[NJ] = {0,1,2,3,4,6,7,8,9,11,12,13,14,15,16,17,18,19,20,22,24,25,26,27,28,30};
    constexpr int PAR[NJ]     = {-1,0,1,2,3,0,5,6,7,0,9,10,11,12,10,14,15,16,17,17,10,20,21,22,23,23};

    float ac[NJ][3];   // column k of ang[slot]; compile-time indices -> registers
    float pp[NJ];      // component k of pos[slot]; kept in registers until flush

    {
        float R[9];
        rodrigues(row[3], row[4], row[5], R);
        ac[0][0] = (k == 0) ? R[0] : ((k == 1) ? R[1] : R[2]);
        ac[0][1] = (k == 0) ? R[3] : ((k == 1) ? R[4] : R[5]);
        ac[0][2] = (k == 0) ? R[6] : ((k == 1) ? R[7] : R[8]);
        pp[0] = off[k] + row[k];
    }

    #pragma unroll
    for (int s = 1; s < NJ; ++s) {
        const int i  = OFF_IDX[s];
        const int pa = PAR[s];
        float L[9];
        rodrigues(row[3*i+3], row[3*i+4], row[3*i+5], L);  // redundant across 3 waves
        const float o0 = off[3*i], o1 = off[3*i+1], o2 = off[3*i+2];  // uniform -> s_load
        pp[s] = o0*ac[pa][0] + o1*ac[pa][1] + o2*ac[pa][2] + pp[pa];
        ac[s][0] = L[0]*ac[pa][0] + L[1]*ac[pa][1] + L[2]*ac[pa][2];
        ac[s][1] = L[3]*ac[pa][0] + L[4]*ac[pa][1] + L[5]*ac[pa][2];
        ac[s][2] = L[6]*ac[pa][0] + L[7]*ac[pa][1] + L[8]*ac[pa][2];
    }

    __syncthreads();                             // all buf reads done in every wave

    // ---- pos transpose into (dead) input region: banks (3r+3s+k)%32 -> 2-way, free ----
    #pragma unroll
    for (int s = 0; s < NJ; ++s)
        wrow[3*s + k] = pp[s];                   // wrow = &buf[r*XDIM], r = lane
    __syncthreads();

    // ---- coalesced flush: consecutive lanes -> consecutive global dwords,
    //      full 64B lines, each line written exactly once ----
    {
        float* oblk = out + (long long)row0 * OUTW;
        #pragma unroll
        for (int j = 0; j < 26; ++j) {           // 192*26 = 4992 = 64*78 exact
            int m = t + j * TPB;
            int rr = m / OUTW;                   // const divisor -> magic mul
            int cc = m - rr * OUTW;
            oblk[m] = buf[rr * XDIM + cc];
        }
    }
}

extern "C" void kernel_launch(void* const* d_in, const int* in_sizes, int n_in,
                              void* d_out, int out_size, void* d_ws, size_t ws_size,
                              hipStream_t stream) {
    const float* x   = (const float*)d_in[0];
    const float* off = (const float*)d_in[1];
    float* out = (float*)d_out;
    const int B = in_sizes[0] / XDIM;      // 262144
    const int grid = B / ROWS;             // 4096
    skel_fk<<<grid, TPB, 0, stream>>>(x, off, out);
}